// Round 5
// baseline (9.734 us; speedup 1.0000x reference)
//
#include <hip/hip_runtime.h>

#define NCOLS 1024
#define NROWS 32
#define MAGIC 0x5AC0FFEEu

// One plain node: 32 blocks (one row each).
// Algebra: p1+p2+v1+v2 = (A+B)(C+D) with
//   A+B = sum_j (y ? exp(-c1) : exp(-s1))  == u
//   C+D = sum_j (y ? exp(s1)  : exp(c1))   == w
// and denom = (yn+ybn)^2 = NCOLS^2 exactly (y in {0,1}), so
//   mean = (sum_rows u*w) * 1/(NROWS*NCOLS^2) = sum * 2^-25 (exact scaling).
// Cross-block: each block release-stores u*w + MAGIC flag; block 0
// acquire-spins, reduces, writes out, resets flags (replay-safe).
__global__ __launch_bounds__(256) void bpmll_flag_kernel(
    const float* __restrict__ c, const int* __restrict__ y,
    float* __restrict__ ws, float* __restrict__ out) {
    const int row = blockIdx.x;
    const int tid = threadIdx.x;
    const int wave = tid >> 6;
    const int lane = tid & 63;

    float* vals = ws;                                   // [0..31] row values
    unsigned int* flags = (unsigned int*)(ws + NROWS);  // [0..31] flags

    // c row interleaved [c1_0, s1_0, c1_1, s1_1, ...]; one float4 = 2 columns
    const float4* __restrict__ crow4 =
        reinterpret_cast<const float4*>(c + (size_t)row * 2 * NCOLS);
    const int2* __restrict__ yrow2 =
        reinterpret_cast<const int2*>(y + (size_t)row * NCOLS);

    float u = 0.f, w = 0.f;
    #pragma unroll
    for (int k = 0; k < 2; ++k) {
        const int idx = k * 256 + tid;       // 512 float4 per row
        const float4 F = crow4[idx];
        const int2  Y = yrow2[idx];
        {
            const bool yy = (Y.x != 0);
            const float a = yy ? F.x : F.y;  // u-select: c1 if y else s1
            const float b = yy ? F.y : F.x;  // w-select: s1 if y else c1
            u += __expf(-a);
            w += __expf(b);
        }
        {
            const bool yy = (Y.y != 0);
            const float a = yy ? F.z : F.w;
            const float b = yy ? F.w : F.z;
            u += __expf(-a);
            w += __expf(b);
        }
    }
    #pragma unroll
    for (int off = 32; off > 0; off >>= 1) {
        u += __shfl_xor(u, off);
        w += __shfl_xor(w, off);
    }
    __shared__ float red[4][2];
    __shared__ float row0val;
    if (lane == 0) { red[wave][0] = u; red[wave][1] = w; }
    __syncthreads();
    if (tid == 0) {
        const float U = red[0][0] + red[1][0] + red[2][0] + red[3][0];
        const float W = red[0][1] + red[1][1] + red[2][1] + red[3][1];
        const float v = U * W;
        if (row == 0) {
            row0val = v;
        } else {
            __hip_atomic_store(&vals[row], v, __ATOMIC_RELAXED,
                               __HIP_MEMORY_SCOPE_AGENT);
            __hip_atomic_store(&flags[row], MAGIC, __ATOMIC_RELEASE,
                               __HIP_MEMORY_SCOPE_AGENT);
        }
    }
    if (row == 0) {
        __syncthreads();
        if (tid < 64) {
            float v = 0.f;
            if (lane == 0) {
                v = row0val;
            } else if (lane < NROWS) {
                while (__hip_atomic_load(&flags[lane], __ATOMIC_ACQUIRE,
                                         __HIP_MEMORY_SCOPE_AGENT) != MAGIC) {
                }
                v = __hip_atomic_load(&vals[lane], __ATOMIC_RELAXED,
                                      __HIP_MEMORY_SCOPE_AGENT);
                // reset for next replay (self-restoring state)
                __hip_atomic_store(&flags[lane], 0u, __ATOMIC_RELAXED,
                                   __HIP_MEMORY_SCOPE_AGENT);
            }
            #pragma unroll
            for (int off = 32; off > 0; off >>= 1) v += __shfl_xor(v, off);
            // * 1/(NROWS * NCOLS^2) = 2^-25 (exact)
            if (lane == 0) out[0] = v * (1.f / 33554432.f);
        }
    }
}

extern "C" void kernel_launch(void* const* d_in, const int* in_sizes, int n_in,
                              void* d_out, int out_size, void* d_ws, size_t ws_size,
                              hipStream_t stream) {
    const float* c = (const float*)d_in[0];
    const int*   y = (const int*)d_in[1];
    float* out = (float*)d_out;
    float* ws  = (float*)d_ws;
    bpmll_flag_kernel<<<NROWS, 256, 0, stream>>>(c, y, ws, out);
}